// Round 5
// baseline (188.883 us; speedup 1.0000x reference)
//
#include <hip/hip_runtime.h>
#include <math.h>

#define S_LEN 512
#define BATCH 16
#define DIN   512
#define DF    512
#define NMIX  10
#define NCHAR 1024
#define DCTX  256
#define M_ROWS (S_LEN*BATCH)   // 8192

// d_out layout (tuple flattened in return order)
#define OFF_CTXOUT 0
#define OFF_ATTN   (S_LEN*BATCH*DCTX)
#define OFF_MEANS  (OFF_ATTN + S_LEN*BATCH*NCHAR)
#define OFF_VARS   (OFF_MEANS + S_LEN*BATCH*NMIX)
#define OFF_WTS    (OFF_VARS  + S_LEN*BATCH*NMIX)

// scratch carved out of the attn output region (overwritten by attn_kernel later)
#define XH_OFF  0
#define W1H_OFF 4194304
#define HH_OFF  4456448
#define W2T_USHORT_OFF 8650752

#define NX4    1048576    // X float4 count
#define NCVT4  1114112    // X + W1 float4 count
#define CVT_BLOCKS 4352
#define W2T_BLOCKS 64

typedef float    f32x16 __attribute__((ext_vector_type(16)));
typedef _Float16 f16x8  __attribute__((ext_vector_type(8)));

__device__ __forceinline__ unsigned short f2h(float x) {
    union { _Float16 h; unsigned short u; } cv;
    cv.h = (_Float16)x;
    return cv.u;
}

// ---------------------------------------------------------------------------
// Kernel 0: convert X,W1 -> f16 scratch; build W2^T (fp32, padded 32 rows).
// ---------------------------------------------------------------------------
__global__ __launch_bounds__(256) void convert_kernel(
    const float* __restrict__ X, const float* __restrict__ W1,
    const float* __restrict__ W2,
    unsigned short* __restrict__ hbase, float* __restrict__ W2T)
{
    const int bid = blockIdx.x;
    if (bid < CVT_BLOCKS) {
        const int i4 = bid*256 + threadIdx.x;
        float4 v = (i4 < NX4) ? ((const float4*)X)[i4]
                              : ((const float4*)W1)[i4 - NX4];
        ushort4 o;
        o.x = f2h(v.x); o.y = f2h(v.y); o.z = f2h(v.z); o.w = f2h(v.w);
        ((ushort4*)hbase)[i4] = o;
    } else {
        const int idx = (bid - CVT_BLOCKS)*256 + threadIdx.x;
        if (idx < 512*32) {
            const int j = idx >> 9, k = idx & 511;
            W2T[idx] = (j < 30) ? W2[k*30 + j] : 0.f;
        }
    }
}

// ---------------------------------------------------------------------------
// Kernel 1: GEMM1 via f16 MFMA 32x32x16, 128x128 tile, BK=64 (m93-style).
// 256 blocks, 4 waves as 2x2 of 64x64; per wave 2x2 accs of 32x32.
// A staging: coalesced uint4, bank-uniform.  B staging: lanes along k ->
// 2-way LDS stores (free); loads L2-hot (W1h shared by all row-blocks).
// ---------------------------------------------------------------------------
__global__ __launch_bounds__(256) void gemm1_kernel(
    const unsigned short* __restrict__ Xh, const unsigned short* __restrict__ W1h,
    const float* __restrict__ b1, unsigned short* __restrict__ Hh)
{
    __shared__ __align__(16) unsigned short As[128*72];   // 18 KB
    __shared__ __align__(16) unsigned short Bs[128*72];   // 18 KB
    const int row0 = (blockIdx.x >> 2) * 128;
    const int n0   = (blockIdx.x & 3)  * 128;
    const int tid  = threadIdx.x;
    const int lane = tid & 63, w = tid >> 6;
    const int wr = (w >> 1) * 64, wc = (w & 1) * 64;
    const int m  = lane & 31,  g  = lane >> 5;
    // A staging: flat = tid + q*256 -> row = flat>>3, colgroup = (flat&7)*8
    const int ar = tid >> 3, ac = (tid & 7) * 8;
    // B staging: kb = tid&63 (lane-major -> 2-way free stores), nb = (tid>>6)*8
    const int kb = tid & 63, nb = (tid >> 6) * 8;

    f32x16 acc00 = {}, acc01 = {}, acc10 = {}, acc11 = {};

    for (int kt = 0; kt < DIN; kt += 64) {
        uint4 av[4], bv[4];
        #pragma unroll
        for (int q = 0; q < 4; q++)
            av[q] = *(const uint4*)(Xh + (size_t)(row0 + ar + q*32)*DIN + kt + ac);
        #pragma unroll
        for (int q = 0; q < 4; q++)
            bv[q] = *(const uint4*)(W1h + (size_t)(kt + kb)*DF + n0 + nb + q*32);
        __syncthreads();
        #pragma unroll
        for (int q = 0; q < 4; q++)
            *(uint4*)(As + (ar + q*32)*72 + ac) = av[q];
        #pragma unroll
        for (int q = 0; q < 4; q++) {
            union { uint4 u; unsigned short s[8]; } p;
            p.u = bv[q];
            #pragma unroll
            for (int i = 0; i < 8; i++)
                Bs[(nb + q*32 + i)*72 + kb] = p.s[i];
        }
        __syncthreads();
        #pragma unroll
        for (int ks = 0; ks < 64; ks += 16) {
            f16x8 a0 = *(const f16x8*)(As + (wr + m)*72      + ks + g*8);
            f16x8 a1 = *(const f16x8*)(As + (wr + 32 + m)*72 + ks + g*8);
            f16x8 b0 = *(const f16x8*)(Bs + (wc + m)*72      + ks + g*8);
            f16x8 b1v= *(const f16x8*)(Bs + (wc + 32 + m)*72 + ks + g*8);
            acc00 = __builtin_amdgcn_mfma_f32_32x32x16_f16(a0, b0,  acc00, 0, 0, 0);
            acc01 = __builtin_amdgcn_mfma_f32_32x32x16_f16(a0, b1v, acc01, 0, 0, 0);
            acc10 = __builtin_amdgcn_mfma_f32_32x32x16_f16(a1, b0,  acc10, 0, 0, 0);
            acc11 = __builtin_amdgcn_mfma_f32_32x32x16_f16(a1, b1v, acc11, 0, 0, 0);
        }
    }
    const int c0 = n0 + wc + m, c1 = n0 + wc + 32 + m;
    const float bb0 = b1[c0], bb1 = b1[c1];
    #pragma unroll
    for (int r = 0; r < 16; r++) {
        const int rowloc = (r & 3) + 8*(r >> 2) + 4*g;
        const int ra = row0 + wr + rowloc;
        const int rb = ra + 32;
        float v;
        v = acc00[r] + bb0; v = v > 0.f ? v : 0.01f*v; Hh[(size_t)ra*DF + c0] = f2h(v);
        v = acc01[r] + bb1; v = v > 0.f ? v : 0.01f*v; Hh[(size_t)ra*DF + c1] = f2h(v);
        v = acc10[r] + bb0; v = v > 0.f ? v : 0.01f*v; Hh[(size_t)rb*DF + c0] = f2h(v);
        v = acc11[r] + bb1; v = v > 0.f ? v : 0.01f*v; Hh[(size_t)rb*DF + c1] = f2h(v);
    }
}

// ---------------------------------------------------------------------------
// Kernel 2: GEMM2 (8192x30, K=512), LDS-staged H, broadcast W2T reads.
// ---------------------------------------------------------------------------
__global__ __launch_bounds__(256) void gemm2_kernel(
    const unsigned short* __restrict__ Hh, const float* __restrict__ W2T,
    const float* __restrict__ b2,
    float* __restrict__ dmeans, float* __restrict__ dvars, float* __restrict__ dwts)
{
    __shared__ __align__(16) unsigned short Hs[32*520];
    const int tid = threadIdx.x;
    const int r0  = blockIdx.x * 32;
    {
        const uint4* src = (const uint4*)(Hh + (size_t)r0*DF);
        #pragma unroll
        for (int i = 0; i < 8; i++) {
            int u   = tid + i*256;
            int row = u >> 6;
            int col = (u & 63) * 8;
            *(uint4*)(Hs + row*520 + col) = src[u];
        }
    }
    __syncthreads();

    const int r  = tid & 31;
    const int j0 = tid >> 5;
    const unsigned short* hrow = Hs + r*520;
    float acc[4] = {0.f, 0.f, 0.f, 0.f};

    for (int k0 = 0; k0 < DF; k0 += 8) {
        union { uint4 u; _Float16 h[8]; } hv;
        hv.u = *(const uint4*)(hrow + k0);
        float wv[4][8];
        #pragma unroll
        for (int q = 0; q < 4; q++) {
            *(float4*)(wv[q])     = *(const float4*)(W2T + (size_t)(j0 + q*8)*DF + k0);
            *(float4*)(wv[q] + 4) = *(const float4*)(W2T + (size_t)(j0 + q*8)*DF + k0 + 4);
        }
        #pragma unroll
        for (int i = 0; i < 8; i++) {
            float hf = (float)hv.h[i];
            acc[0] = fmaf(hf, wv[0][i], acc[0]);
            acc[1] = fmaf(hf, wv[1][i], acc[1]);
            acc[2] = fmaf(hf, wv[2][i], acc[2]);
            acc[3] = fmaf(hf, wv[3][i], acc[3]);
        }
    }
    const int row = r0 + r;
    #pragma unroll
    for (int q = 0; q < 4; q++) {
        const int j = j0 + q*8;
        if (j >= 30) continue;
        float dot = acc[q] + b2[j];
        float sp  = fmaxf(dot, 0.f) + log1pf(__expf(-fabsf(dot)));
        if (j < 10)       dmeans[row*NMIX + j]      = sp / 25.0f;
        else if (j < 20)  dvars [row*NMIX + (j-10)] = fminf(fmaxf(sp, 0.01f), 100.f);
        else              dwts  [row*NMIX + (j-20)] = sp;
    }
}

// ---------------------------------------------------------------------------
// Kernel 3: parallel inclusive scan over S per (b,k) pair.
// ---------------------------------------------------------------------------
__global__ __launch_bounds__(512) void scan_kernel(
    const float* __restrict__ init_means, float* __restrict__ means)
{
    const int p    = blockIdx.x;
    const int s    = threadIdx.x;
    const int lane = s & 63;
    const int wid  = s >> 6;

    float x = means[s*(BATCH*NMIX) + p];
    #pragma unroll
    for (int d = 1; d < 64; d <<= 1) {
        float tv = __shfl_up(x, d, 64);
        if (lane >= d) x += tv;
    }
    __shared__ float wsum[8];
    if (lane == 63) wsum[wid] = x;
    __syncthreads();
    float off = init_means[p];
    for (int i = 0; i < wid; i++) off += wsum[i];
    x += off;
    means[s*(BATCH*NMIX) + p] = x;
}

// ---------------------------------------------------------------------------
// Kernel 4: attention weights.
// ---------------------------------------------------------------------------
__global__ __launch_bounds__(256) void attn_kernel(
    const float* __restrict__ means, const float* __restrict__ vars,
    const float* __restrict__ wts,   float* __restrict__ attn)
{
    const int row = blockIdx.x;
    const int tid = threadIdx.x;
    float m[NMIX], v[NMIX], w[NMIX];
    #pragma unroll
    for (int k = 0; k < NMIX; k++) {
        m[k] = means[row*NMIX + k];
        v[k] = vars [row*NMIX + k];
        w[k] = wts  [row*NMIX + k];
    }
    const int t0 = tid * 4;
    float o[4];
    #pragma unroll
    for (int i = 0; i < 4; i++) {
        const float t = (float)(t0 + i);
        float sum = 0.f;
        #pragma unroll
        for (int k = 0; k < NMIX; k++) {
            float d = t - m[k];
            sum += w[k] * __expf(-d*d*v[k]);
        }
        o[i] = sum;
    }
    *(float4*)(attn + (size_t)row*NCHAR + t0) = make_float4(o[0],o[1],o[2],o[3]);
}

// ---------------------------------------------------------------------------
// Kernel 5: attended contexts via f16 MFMA, BOTH operands LDS-staged.
// Grid XCD-swizzled: the 4 d-blocks sharing an A-tile are 8 apart in
// blockIdx -> same XCD under round-robin dispatch -> A-tile L2 reuse.
// ---------------------------------------------------------------------------
__global__ __launch_bounds__(256) void ctx_mfma_kernel(
    const float* __restrict__ attn, const float* __restrict__ ctx,
    float* __restrict__ out)
{
    __shared__ __align__(16) unsigned short As[64*72];
    __shared__ __align__(16) unsigned short Bs[64*72];
    const int bid  = blockIdx.x;
    // swizzle: xcd = bid&7, dpart = (bid>>3)&3, group = (bid>>5)*8 + xcd
    const int grp  = ((bid >> 5) << 3) | (bid & 7);   // 0..127 = (b, s-tile)
    const int b    = grp >> 3;
    const int s0   = (grp & 7) * 64;
    const int d0   = ((bid >> 3) & 3) * 64;
    const int tid  = threadIdx.x;
    const int lane = tid & 63, w = tid >> 6;
    const int wr = (w >> 1) * 32, wc = (w & 1) * 32;
    const int m  = lane & 31,  g  = lane >> 5;
    const int tb = tid & 63,   wb = tid >> 6;

    f32x16 acc = {};
    const float* arow = attn + (size_t)b*NCHAR;
    const float* brow = ctx  + (size_t)b*DCTX + d0 + wb*16;

    for (int kt = 0; kt < NCHAR; kt += 64) {
        float4 a4[4];
        #pragma unroll
        for (int q = 0; q < 4; q++) {
            int flat = tid + q*256;
            int sl = flat >> 4;
            int t0 = (flat & 15) * 4;
            a4[q] = *(const float4*)(arow + (size_t)(s0+sl)*(BATCH*NCHAR) + kt + t0);
        }
        float4 b4[4];
        #pragma unroll
        for (int q = 0; q < 4; q++)
            b4[q] = *(const float4*)(brow + (size_t)(kt+tb)*(BATCH*DCTX) + q*4);
        __syncthreads();
        #pragma unroll
        for (int q = 0; q < 4; q++) {
            int flat = tid + q*256;
            int sl = flat >> 4;
            int t0 = (flat & 15) * 4;
            unsigned int lo = (unsigned int)f2h(a4[q].x) | ((unsigned int)f2h(a4[q].y) << 16);
            unsigned int hi = (unsigned int)f2h(a4[q].z) | ((unsigned int)f2h(a4[q].w) << 16);
            *(uint2*)(As + sl*72 + t0) = make_uint2(lo, hi);
        }
        #pragma unroll
        for (int q = 0; q < 4; q++) {
            Bs[(wb*16 + q*4 + 0)*72 + tb] = f2h(b4[q].x);
            Bs[(wb*16 + q*4 + 1)*72 + tb] = f2h(b4[q].y);
            Bs[(wb*16 + q*4 + 2)*72 + tb] = f2h(b4[q].z);
            Bs[(wb*16 + q*4 + 3)*72 + tb] = f2h(b4[q].w);
        }
        __syncthreads();
        #pragma unroll
        for (int ks = 0; ks < 64; ks += 16) {
            f16x8 af = *(const f16x8*)(As + (wr+m)*72 + ks + g*8);
            f16x8 bf = *(const f16x8*)(Bs + (wc+m)*72 + ks + g*8);
            acc = __builtin_amdgcn_mfma_f32_32x32x16_f16(af, bf, acc, 0, 0, 0);
        }
    }
    #pragma unroll
    for (int r = 0; r < 16; r++) {
        int rowloc = (r & 3) + 8*(r >> 2) + 4*g;
        int s = s0 + wr + rowloc;
        out[(size_t)s*(BATCH*DCTX) + b*DCTX + d0 + wc + m] = acc[r];
    }
}

// ---------------------------------------------------------------------------
extern "C" void kernel_launch(void* const* d_in, const int* in_sizes, int n_in,
                              void* d_out, int out_size, void* d_ws, size_t ws_size,
                              hipStream_t stream)
{
    const float* X     = (const float*)d_in[0];
    const float* ctx   = (const float*)d_in[1];
    const float* initm = (const float*)d_in[2];
    const float* W1    = (const float*)d_in[3];
    const float* b1    = (const float*)d_in[4];
    const float* W2    = (const float*)d_in[5];
    const float* b2    = (const float*)d_in[6];

    float* out      = (float*)d_out;
    float* out_ctx  = out + OFF_CTXOUT;
    float* out_attn = out + OFF_ATTN;
    float* out_mean = out + OFF_MEANS;
    float* out_var  = out + OFF_VARS;
    float* out_wts  = out + OFF_WTS;

    unsigned short* hbase = (unsigned short*)out_attn;
    unsigned short* Xh    = hbase + XH_OFF;
    unsigned short* W1h   = hbase + W1H_OFF;
    unsigned short* Hh    = hbase + HH_OFF;
    float*          W2T   = (float*)(hbase + W2T_USHORT_OFF);

    convert_kernel<<<CVT_BLOCKS + W2T_BLOCKS, 256, 0, stream>>>(X, W1, W2, hbase, W2T);
    gemm1_kernel<<<(M_ROWS/128)*(DF/128), 256, 0, stream>>>(Xh, W1h, b1, Hh);
    gemm2_kernel<<<M_ROWS/32, 256, 0, stream>>>(Hh, W2T, b2, out_mean, out_var, out_wts);
    scan_kernel<<<BATCH*NMIX, 512, 0, stream>>>(initm, out_mean);
    attn_kernel<<<M_ROWS, 256, 0, stream>>>(out_mean, out_var, out_wts, out_attn);
    ctx_mfma_kernel<<<16*8*4, 256, 0, stream>>>(out_attn, ctx, out_ctx);
}

// Round 6
// 172.119 us; speedup vs baseline: 1.0974x; 1.0974x over previous
//
#include <hip/hip_runtime.h>
#include <math.h>

#define S_LEN 512
#define BATCH 16
#define DIN   512
#define DF    512
#define NMIX  10
#define NCHAR 1024
#define DCTX  256
#define M_ROWS (S_LEN*BATCH)   // 8192

// d_out layout (tuple flattened in return order)
#define OFF_CTXOUT 0
#define OFF_ATTN   (S_LEN*BATCH*DCTX)
#define OFF_MEANS  (OFF_ATTN + S_LEN*BATCH*NCHAR)
#define OFF_VARS   (OFF_MEANS + S_LEN*BATCH*NMIX)
#define OFF_WTS    (OFF_VARS  + S_LEN*BATCH*NMIX)

// scratch layout in d_ws (byte offsets; ws_size = 256 MiB per fill evidence)
#define WS_XH    0           // f16  8 MB   (8192x512)
#define WS_W1H   (8u<<20)    // f16  512 KB (512x512)
#define WS_W2T   (9u<<20)    // f32  64 KB  (32x512 padded)
#define WS_HH    (10u<<20)   // f16  8 MB   (8192x512)
#define WS_CTXH  (18u<<20)   // f16  8 MB   (1024x16x256)
#define WS_ATTNH (26u<<20)   // f16  16.8 MB(512x16x1024)

#define NX4     1048576   // X float4 count
#define NW14    65536     // W1 float4 count
#define NCTX4   1048576   // ctx float4 count
#define CVT4    (NX4 + NW14 + NCTX4)           // 2162688
#define CVT_BLOCKS (CVT4/256)                  // 8448
#define W2T_BLOCKS 64

typedef float    f32x16 __attribute__((ext_vector_type(16)));
typedef _Float16 f16x8  __attribute__((ext_vector_type(8)));

__device__ __forceinline__ unsigned short f2h(float x) {
    union { _Float16 h; unsigned short u; } cv;
    cv.h = (_Float16)x;
    return cv.u;
}
__device__ __forceinline__ ushort4 cvt4(float4 v) {
    ushort4 o; o.x = f2h(v.x); o.y = f2h(v.y); o.z = f2h(v.z); o.w = f2h(v.w);
    return o;
}

// ---------------------------------------------------------------------------
// Kernel 0: convert X,W1,ctx -> f16 scratch; build W2^T (fp32, 32 rows).
// ---------------------------------------------------------------------------
__global__ __launch_bounds__(256) void convert_kernel(
    const float* __restrict__ X, const float* __restrict__ W1,
    const float* __restrict__ ctx, const float* __restrict__ W2,
    unsigned short* __restrict__ Xh, unsigned short* __restrict__ W1h,
    unsigned short* __restrict__ ctxh, float* __restrict__ W2T)
{
    const int bid = blockIdx.x;
    if (bid < CVT_BLOCKS) {
        const int i4 = bid*256 + threadIdx.x;
        if (i4 < NX4) {
            ((ushort4*)Xh)[i4] = cvt4(((const float4*)X)[i4]);
        } else if (i4 < NX4 + NW14) {
            ((ushort4*)W1h)[i4 - NX4] = cvt4(((const float4*)W1)[i4 - NX4]);
        } else {
            const int j = i4 - NX4 - NW14;
            ((ushort4*)ctxh)[j] = cvt4(((const float4*)ctx)[j]);
        }
    } else {
        const int idx = (bid - CVT_BLOCKS)*256 + threadIdx.x;
        if (idx < 512*32) {
            const int j = idx >> 9, k = idx & 511;
            W2T[idx] = (j < 30) ? W2[k*30 + j] : 0.f;
        }
    }
}

// ---------------------------------------------------------------------------
// Kernel 1: GEMM1 via f16 MFMA 32x32x16, 64x64 tiles (round-4 proven config:
// 1024 blocks -> 4 blocks/CU, 16 waves/CU).
// ---------------------------------------------------------------------------
__global__ __launch_bounds__(256) void gemm1_kernel(
    const unsigned short* __restrict__ Xh, const unsigned short* __restrict__ W1h,
    const float* __restrict__ b1, unsigned short* __restrict__ Hh)
{
    __shared__ __align__(16) unsigned short As[64*72];
    __shared__ __align__(16) unsigned short Bs[64*72];
    const int row0 = (blockIdx.x >> 3) * 64;
    const int n0   = (blockIdx.x & 7)  * 64;
    const int tid  = threadIdx.x;
    const int lane = tid & 63, w = tid >> 6;
    const int wr = (w >> 1) * 32, wc = (w & 1) * 32;
    const int m  = lane & 31,  g  = lane >> 5;
    const int sa = tid >> 2,   ka = (tid & 3) * 16;
    const int kb = tid & 63,   wb = tid >> 6;

    f32x16 acc = {};

    for (int kt = 0; kt < DIN; kt += 64) {
        uint4 av0 = *(const uint4*)(Xh  + (size_t)(row0+sa)*DIN + kt + ka);
        uint4 av1 = *(const uint4*)(Xh  + (size_t)(row0+sa)*DIN + kt + ka + 8);
        uint4 bv0 = *(const uint4*)(W1h + (size_t)(kt+kb)*DF + n0 + wb*16);
        uint4 bv1 = *(const uint4*)(W1h + (size_t)(kt+kb)*DF + n0 + wb*16 + 8);
        __syncthreads();
        *(uint4*)(As + sa*72 + ka)     = av0;
        *(uint4*)(As + sa*72 + ka + 8) = av1;
        {
            union { uint4 u; unsigned short s[8]; } p0, p1;
            p0.u = bv0; p1.u = bv1;
            #pragma unroll
            for (int i = 0; i < 8; i++) Bs[(wb*16 + i)*72 + kb]     = p0.s[i];
            #pragma unroll
            for (int i = 0; i < 8; i++) Bs[(wb*16 + 8 + i)*72 + kb] = p1.s[i];
        }
        __syncthreads();
        #pragma unroll
        for (int ks = 0; ks < 64; ks += 16) {
            f16x8 af = *(const f16x8*)(As + (wr+m)*72 + ks + g*8);
            f16x8 bf = *(const f16x8*)(Bs + (wc+m)*72 + ks + g*8);
            acc = __builtin_amdgcn_mfma_f32_32x32x16_f16(af, bf, acc, 0, 0, 0);
        }
    }
    const int ncol = n0 + wc + m;
    const float bb = b1[ncol];
    #pragma unroll
    for (int r = 0; r < 16; r++) {
        const int rowloc = (r & 3) + 8*(r >> 2) + 4*g;
        const int row = row0 + wr + rowloc;
        float v = acc[r] + bb;
        v = v > 0.f ? v : 0.01f * v;
        Hh[(size_t)row*DF + ncol] = f2h(v);
    }
}

// ---------------------------------------------------------------------------
// Kernel 2: GEMM2 (8192x30, K=512), LDS-staged H, broadcast W2T reads.
// ---------------------------------------------------------------------------
__global__ __launch_bounds__(256) void gemm2_kernel(
    const unsigned short* __restrict__ Hh, const float* __restrict__ W2T,
    const float* __restrict__ b2,
    float* __restrict__ dmeans, float* __restrict__ dvars, float* __restrict__ dwts)
{
    __shared__ __align__(16) unsigned short Hs[32*520];
    const int tid = threadIdx.x;
    const int r0  = blockIdx.x * 32;
    {
        const uint4* src = (const uint4*)(Hh + (size_t)r0*DF);
        #pragma unroll
        for (int i = 0; i < 8; i++) {
            int u   = tid + i*256;
            int row = u >> 6;
            int col = (u & 63) * 8;
            *(uint4*)(Hs + row*520 + col) = src[u];
        }
    }
    __syncthreads();

    const int r  = tid & 31;
    const int j0 = tid >> 5;
    const unsigned short* hrow = Hs + r*520;
    float acc[4] = {0.f, 0.f, 0.f, 0.f};

    for (int k0 = 0; k0 < DF; k0 += 8) {
        union { uint4 u; _Float16 h[8]; } hv;
        hv.u = *(const uint4*)(hrow + k0);
        float wv[4][8];
        #pragma unroll
        for (int q = 0; q < 4; q++) {
            *(float4*)(wv[q])     = *(const float4*)(W2T + (size_t)(j0 + q*8)*DF + k0);
            *(float4*)(wv[q] + 4) = *(const float4*)(W2T + (size_t)(j0 + q*8)*DF + k0 + 4);
        }
        #pragma unroll
        for (int i = 0; i < 8; i++) {
            float hf = (float)hv.h[i];
            acc[0] = fmaf(hf, wv[0][i], acc[0]);
            acc[1] = fmaf(hf, wv[1][i], acc[1]);
            acc[2] = fmaf(hf, wv[2][i], acc[2]);
            acc[3] = fmaf(hf, wv[3][i], acc[3]);
        }
    }
    const int row = r0 + r;
    #pragma unroll
    for (int q = 0; q < 4; q++) {
        const int j = j0 + q*8;
        if (j >= 30) continue;
        float dot = acc[q] + b2[j];
        float sp  = fmaxf(dot, 0.f) + log1pf(__expf(-fabsf(dot)));
        if (j < 10)       dmeans[row*NMIX + j]      = sp / 25.0f;
        else if (j < 20)  dvars [row*NMIX + (j-10)] = fminf(fmaxf(sp, 0.01f), 100.f);
        else              dwts  [row*NMIX + (j-20)] = sp;
    }
}

// ---------------------------------------------------------------------------
// Kernel 3: parallel inclusive scan over S per (b,k) pair.
// ---------------------------------------------------------------------------
__global__ __launch_bounds__(512) void scan_kernel(
    const float* __restrict__ init_means, float* __restrict__ means)
{
    const int p    = blockIdx.x;
    const int s    = threadIdx.x;
    const int lane = s & 63;
    const int wid  = s >> 6;

    float x = means[s*(BATCH*NMIX) + p];
    #pragma unroll
    for (int d = 1; d < 64; d <<= 1) {
        float tv = __shfl_up(x, d, 64);
        if (lane >= d) x += tv;
    }
    __shared__ float wsum[8];
    if (lane == 63) wsum[wid] = x;
    __syncthreads();
    float off = init_means[p];
    for (int i = 0; i < wid; i++) off += wsum[i];
    x += off;
    means[s*(BATCH*NMIX) + p] = x;
}

// ---------------------------------------------------------------------------
// Kernel 4: attention weights -> f32 output AND f16 scratch copy.
// ---------------------------------------------------------------------------
__global__ __launch_bounds__(256) void attn_kernel(
    const float* __restrict__ means, const float* __restrict__ vars,
    const float* __restrict__ wts,   float* __restrict__ attn,
    unsigned short* __restrict__ attnh)
{
    const int row = blockIdx.x;
    const int tid = threadIdx.x;
    float m[NMIX], v[NMIX], w[NMIX];
    #pragma unroll
    for (int k = 0; k < NMIX; k++) {
        m[k] = means[row*NMIX + k];
        v[k] = vars [row*NMIX + k];
        w[k] = wts  [row*NMIX + k];
    }
    const int t0 = tid * 4;
    float o[4];
    #pragma unroll
    for (int i = 0; i < 4; i++) {
        const float t = (float)(t0 + i);
        float sum = 0.f;
        #pragma unroll
        for (int k = 0; k < NMIX; k++) {
            float d = t - m[k];
            sum += w[k] * __expf(-d*d*v[k]);
        }
        o[i] = sum;
    }
    *(float4*)(attn + (size_t)row*NCHAR + t0) = make_float4(o[0],o[1],o[2],o[3]);
    ushort4 h; h.x = f2h(o[0]); h.y = f2h(o[1]); h.z = f2h(o[2]); h.w = f2h(o[3]);
    *(ushort4*)(attnh + (size_t)row*NCHAR + t0) = h;
}

// ---------------------------------------------------------------------------
// Kernel 5: attended contexts via f16 MFMA, f16 inputs (no in-loop convert).
// 64x64 tiles, plain block mapping (no swizzle).
// ---------------------------------------------------------------------------
__global__ __launch_bounds__(256) void ctx_mfma_kernel(
    const unsigned short* __restrict__ attnh, const unsigned short* __restrict__ ctxh,
    float* __restrict__ out)
{
    __shared__ __align__(16) unsigned short As[64*72];
    __shared__ __align__(16) unsigned short Bs[64*72];
    const int bid  = blockIdx.x;
    const int b    = bid >> 5;
    const int rem  = bid & 31;
    const int s0   = (rem >> 2) * 64;
    const int d0   = (rem & 3)  * 64;
    const int tid  = threadIdx.x;
    const int lane = tid & 63, w = tid >> 6;
    const int wr = (w >> 1) * 32, wc = (w & 1) * 32;
    const int m  = lane & 31,  g  = lane >> 5;
    const int sl = tid >> 2,   tq = (tid & 3) * 16;   // A staging
    const int tb = tid & 63,   db = (tid >> 6) * 16;  // B staging

    f32x16 acc = {};
    const unsigned short* abase = attnh + (size_t)(s0+sl)*(BATCH*NCHAR) + b*NCHAR + tq;
    const unsigned short* bbase = ctxh  + (size_t)b*DCTX + d0 + db;

    for (int kt = 0; kt < NCHAR; kt += 64) {
        uint4 a0 = *(const uint4*)(abase + kt);
        uint4 a1 = *(const uint4*)(abase + kt + 8);
        uint4 bv0 = *(const uint4*)(bbase + (size_t)(kt+tb)*(BATCH*DCTX));
        uint4 bv1 = *(const uint4*)(bbase + (size_t)(kt+tb)*(BATCH*DCTX) + 8);
        __syncthreads();
        *(uint4*)(As + sl*72 + tq)     = a0;
        *(uint4*)(As + sl*72 + tq + 8) = a1;
        {
            union { uint4 u; unsigned short s[8]; } p0, p1;
            p0.u = bv0; p1.u = bv1;
            #pragma unroll
            for (int i = 0; i < 8; i++) Bs[(db + i)*72 + tb]     = p0.s[i];
            #pragma unroll
            for (int i = 0; i < 8; i++) Bs[(db + 8 + i)*72 + tb] = p1.s[i];
        }
        __syncthreads();
        #pragma unroll
        for (int ks = 0; ks < 64; ks += 16) {
            f16x8 af = *(const f16x8*)(As + (wr+m)*72 + ks + g*8);
            f16x8 bf = *(const f16x8*)(Bs + (wc+m)*72 + ks + g*8);
            acc = __builtin_amdgcn_mfma_f32_32x32x16_f16(af, bf, acc, 0, 0, 0);
        }
    }
    #pragma unroll
    for (int r = 0; r < 16; r++) {
        int rowloc = (r & 3) + 8*(r >> 2) + 4*g;
        int s = s0 + wr + rowloc;
        out[(size_t)s*(BATCH*DCTX) + b*DCTX + d0 + wc + m] = acc[r];
    }
}

// ---------------------------------------------------------------------------
extern "C" void kernel_launch(void* const* d_in, const int* in_sizes, int n_in,
                              void* d_out, int out_size, void* d_ws, size_t ws_size,
                              hipStream_t stream)
{
    const float* X     = (const float*)d_in[0];
    const float* ctx   = (const float*)d_in[1];
    const float* initm = (const float*)d_in[2];
    const float* W1    = (const float*)d_in[3];
    const float* b1    = (const float*)d_in[4];
    const float* W2    = (const float*)d_in[5];
    const float* b2    = (const float*)d_in[6];

    float* out      = (float*)d_out;
    float* out_ctx  = out + OFF_CTXOUT;
    float* out_attn = out + OFF_ATTN;
    float* out_mean = out + OFF_MEANS;
    float* out_var  = out + OFF_VARS;
    float* out_wts  = out + OFF_WTS;

    char* ws = (char*)d_ws;
    unsigned short* Xh    = (unsigned short*)(ws + WS_XH);
    unsigned short* W1h   = (unsigned short*)(ws + WS_W1H);
    float*          W2T   = (float*)         (ws + WS_W2T);
    unsigned short* Hh    = (unsigned short*)(ws + WS_HH);
    unsigned short* ctxh  = (unsigned short*)(ws + WS_CTXH);
    unsigned short* attnh = (unsigned short*)(ws + WS_ATTNH);

    convert_kernel<<<CVT_BLOCKS + W2T_BLOCKS, 256, 0, stream>>>(
        X, W1, ctx, W2, Xh, W1h, ctxh, W2T);
    gemm1_kernel<<<(M_ROWS/64)*(DF/64), 256, 0, stream>>>(Xh, W1h, b1, Hh);
    gemm2_kernel<<<M_ROWS/32, 256, 0, stream>>>(Hh, W2T, b2, out_mean, out_var, out_wts);
    scan_kernel<<<BATCH*NMIX, 512, 0, stream>>>(initm, out_mean);
    attn_kernel<<<M_ROWS, 256, 0, stream>>>(out_mean, out_var, out_wts, out_attn, attnh);
    ctx_mfma_kernel<<<16*8*4, 256, 0, stream>>>(attnh, ctxh, out_ctx);
}